// Round 9
// baseline (206.316 us; speedup 1.0000x reference)
//
#include <hip/hip_runtime.h>
#include <hip/hip_bf16.h>

#define NB 4
#define NN 2048
#define FIN 64
#define DOUT 128

typedef __hip_bfloat16 bf16;
typedef __attribute__((ext_vector_type(8))) short short8;
typedef __attribute__((ext_vector_type(4))) float f32x4;
typedef __attribute__((ext_vector_type(4))) int int4v;

static __device__ __forceinline__ float bf2f(bf16 v) { return __bfloat162float(v); }
static __device__ __forceinline__ bf16  f2bf(float v) { return __float2bfloat16(v); }
static __device__ __forceinline__ unsigned bfbits(float v) {
    bf16 h = __float2bfloat16(v);
    return (unsigned)*reinterpret_cast<unsigned short*>(&h);
}

// ---------------- R8 fragment-linear operand layouts (kept) ----------------
// Layer1 (H=4, D=32):  qA/kA: [(b*4+hd)][t16][lane][8];  vT: [(b*4+hd)][kt][mt][ks2][lane][8]
// Layer2 (H=1, D=128): qA/kA: [b][t16][ks][lane][8];     vT: [b][kt][mt 0..7][ks2][lane][8]

// ---------------- Kernel 1: q1,k1,vT (bf16 fragment-linear), proj (fp32) ----------------
__global__ __launch_bounds__(256) void k_gemm1(
    const float* __restrict__ x,
    const float* __restrict__ q1w, const float* __restrict__ q1b,
    const float* __restrict__ k1w, const float* __restrict__ k1b,
    const float* __restrict__ v1w, const float* __restrict__ v1b,
    const float* __restrict__ pw,
    bf16* __restrict__ qA, bf16* __restrict__ kA, bf16* __restrict__ vT,
    float* __restrict__ proj)
{
    __shared__ float At[64][65];
    __shared__ float Wt[64][65];
    const int rb = blockIdx.x;
    const int cb = blockIdx.y;
    const int mat = cb >> 1;
    const int c0 = (cb & 1) * 64;
    const float* W    = (mat==0)? q1w : (mat==1)? k1w : (mat==2)? v1w : pw;
    const float* bias = (mat==0)? q1b : (mat==1)? k1b : (mat==2)? v1b : nullptr;
    const int t = threadIdx.x;
    const int row0 = rb * 64;
    for (int e = t; e < 1024; e += 256) {
        int r = e >> 4, c4 = e & 15;
        *(float4*)&At[r][c4*4] = *(const float4*)&x[(size_t)(row0 + r)*FIN + c4*4];
        *(float4*)&Wt[r][c4*4] = *(const float4*)&W[(size_t)r*DOUT + c0 + c4*4];
    }
    __syncthreads();
    const int ty = t >> 4, tx = t & 15;
    float acc[4][4] = {};
    #pragma unroll 8
    for (int k = 0; k < 64; ++k) {
        float av[4], bv[4];
        #pragma unroll
        for (int i = 0; i < 4; ++i) av[i] = At[ty*4+i][k];
        #pragma unroll
        for (int j = 0; j < 4; ++j) bv[j] = Wt[k][tx*4+j];
        #pragma unroll
        for (int i = 0; i < 4; ++i)
            #pragma unroll
            for (int j = 0; j < 4; ++j)
                acc[i][j] = fmaf(av[i], bv[j], acc[i][j]);
    }
    #pragma unroll
    for (int i = 0; i < 4; ++i) {
        int gr = row0 + ty*4 + i;
        int b = gr >> 11, n = gr & 2047;
        #pragma unroll
        for (int j = 0; j < 4; ++j) {
            int gc = c0 + tx*4 + j;
            float v = acc[i][j] + (bias ? bias[gc] : 0.f);
            if (mat == 3) { proj[(size_t)gr*DOUT + gc] = v; continue; }
            int hd = gc >> 5, d32 = gc & 31;
            if (mat == 2) {
                int kt = n >> 6, ks2 = (n >> 5) & 1, q4k = (n >> 3) & 3, jk = n & 7;
                int mt = d32 >> 4, n16d = d32 & 15;
                size_t idx = ((((size_t)(b*4+hd)*32 + kt)*2 + mt)*2 + ks2)*512
                             + (size_t)(q4k*16 + n16d)*8 + jk;
                vT[idx] = f2bf(v);
            } else {
                size_t idx = ((size_t)(b*4+hd)*128 + (n >> 4))*512
                             + (size_t)((d32 >> 3)*16 + (n & 15))*8 + (d32 & 7);
                if (mat == 0) qA[idx] = f2bf(v); else kA[idx] = f2bf(v);
            }
        }
    }
}

// ---------------- Kernel 3: q2,k2,vT (fragment-linear layer2) = h @ W (+bias) ----------------
__global__ __launch_bounds__(256) void k_gemm2(
    const bf16* __restrict__ h,
    const float* __restrict__ q2w, const float* __restrict__ q2b,
    const float* __restrict__ k2w, const float* __restrict__ k2b,
    const float* __restrict__ v2w, const float* __restrict__ v2b,
    bf16* __restrict__ qA, bf16* __restrict__ kA, bf16* __restrict__ vT)
{
    __shared__ float At[64][65];
    __shared__ float Wt[64][65];
    const int rb = blockIdx.x, cb = blockIdx.y;
    const int mat = cb >> 1, c0 = (cb & 1)*64;
    const float* W    = (mat==0)? q2w : (mat==1)? k2w : v2w;
    const float* bias = (mat==0)? q2b : (mat==1)? k2b : v2b;
    const int t = threadIdx.x, ty = t >> 4, tx = t & 15, row0 = rb*64;
    float acc[4][4] = {};
    for (int kc = 0; kc < 2; ++kc) {
        __syncthreads();
        for (int e = t; e < 512; e += 256) {
            int r = e >> 3, c8 = e & 7;
            short8 hv = *(const short8*)&h[(size_t)(row0+r)*DOUT + kc*64 + c8*8];
            #pragma unroll
            for (int u = 0; u < 8; ++u)
                At[r][c8*8 + u] = __uint_as_float(((unsigned)(unsigned short)hv[u]) << 16);
        }
        for (int e = t; e < 1024; e += 256) {
            int r = e >> 4, c4 = e & 15;
            *(float4*)&Wt[r][c4*4] = *(const float4*)&W[(size_t)(kc*64+r)*DOUT + c0 + c4*4];
        }
        __syncthreads();
        #pragma unroll 8
        for (int k = 0; k < 64; ++k) {
            float av[4], bv[4];
            #pragma unroll
            for (int i = 0; i < 4; ++i) av[i] = At[ty*4+i][k];
            #pragma unroll
            for (int j = 0; j < 4; ++j) bv[j] = Wt[k][tx*4+j];
            #pragma unroll
            for (int i = 0; i < 4; ++i)
                #pragma unroll
                for (int j = 0; j < 4; ++j)
                    acc[i][j] = fmaf(av[i], bv[j], acc[i][j]);
        }
    }
    #pragma unroll
    for (int i = 0; i < 4; ++i) {
        int gr = row0 + ty*4 + i;
        int b = gr >> 11, n = gr & 2047;
        #pragma unroll
        for (int j = 0; j < 4; ++j) {
            int gc = c0 + tx*4 + j;
            float v = acc[i][j] + bias[gc];
            if (mat == 2) {
                int kt = n >> 6, ks2 = (n >> 5) & 1, q4k = (n >> 3) & 3, jk = n & 7;
                int mt = gc >> 4, n16d = gc & 15;
                size_t idx = (((size_t)b*32 + kt)*8 + mt)*1024 + (size_t)ks2*512
                             + (size_t)(q4k*16 + n16d)*8 + jk;
                vT[idx] = f2bf(v);
            } else {
                int ks = gc >> 5, q4 = (gc >> 3) & 3, jj = gc & 7;
                size_t idx = ((size_t)b*128 + (n >> 4))*2048 + (size_t)ks*512
                             + (size_t)(q4*16 + (n & 15))*8 + jj;
                if (mat == 0) qA[idx] = f2bf(v); else kA[idx] = f2bf(v);
            }
        }
    }
}

// ---------------- MFMA flash attention v9 ----------------
// Model (r5..r8): attn time = F(~15us) + bytes/6.3TB/s — same wall as memset; only
// BYTES matter. MODE1 NQ=4 alone halves the grid (flat, r6). R9: NQ=4 + 4-way KEY
// SPLIT -> 512 blocks (full chip), traffic 256->128MB. Blocks write partial O'
// (bf16, undivided) + partial denom; k_merge_ln sums, divides, +proj, LayerNorm.
// NW=4/256thr + launch_bounds(256,2): 256-VGPR cap (persistent 192 = qf64+acc128);
// interleaved halves cap transients. MODE 0 unchanged from r8.
template<int D, int MODE, int NW, int NQ>
__global__ __launch_bounds__(NW*64, 2) void k_attn_mfma(
    const bf16* __restrict__ qA, const bf16* __restrict__ kA, const bf16* __restrict__ vT,
    const float* __restrict__ proj, const float* __restrict__ lng, const float* __restrict__ lnb,
    bf16* __restrict__ hout, float* __restrict__ fout, float* __restrict__ dout)
{
    constexpr int NKS = D / 32;     // 32-dim k-steps in S^T
    constexpr int NMT = D / 16;     // 16-dim m-tiles of O^T
    constexpr int KSP = (MODE == 1) ? 4 : 1;            // key splits
    constexpr int ITERS = NN / (64 * NW * KSP);

    __shared__ float lbuf[NW][NQ*16];
    constexpr int OSW = (MODE == 0) ? (D + 1) : (D + 2);
    __shared__ char oS_raw[(size_t)NW * NQ*16 * OSW * ((MODE == 0) ? 4 : 2)];

    const float scale = (D == 32) ? 0.17677669529663687f : 0.08838834764831843f;

    // XCD-aware swizzle (xcd = linear_wg % 8).
    const unsigned wg  = blockIdx.x + (unsigned)gridDim.x * blockIdx.y;
    const unsigned xcd = wg & 7u;
    const unsigned idx = wg >> 3;
    int qb, bh, ksp = 0;
    if constexpr (MODE == 0) {
        // 512 wgs: idx 0..63. 2 adjacent heads per XCD; 32 q-blocks.
        bh = (int)((xcd << 1) | (idx >> 5));   // 0..15
        qb = (int)(idx & 31u);                 // 0..31
    } else {
        // 512 wgs: idx 0..63. b per XCD-pair; qb 0..31; ksp 0..3.
        bh = (int)(xcd >> 1);                  // 0..3
        qb = (int)(((xcd & 1u) << 4) | (idx & 15u));  // 0..31
        ksp = (int)(idx >> 4);                 // 0..3
    }

    const int b  = (MODE == 0) ? (bh >> 2) : bh;
    const int hd = (MODE == 0) ? (bh & 3) : 0;
    const int q0 = qb * (16*NQ);
    const int wave = threadIdx.x >> 6, lane = threadIdx.x & 63;
    const int n16 = lane & 15, q4 = lane >> 4;
    const int lane8 = lane * 8;

    // fragment-linear bases
    const short* qbase, * kbase, * vbase;
    if constexpr (MODE == 0) {
        qbase = (const short*)qA + (size_t)(b*4 + hd)*128*512;
        kbase = (const short*)kA + (size_t)(b*4 + hd)*128*512;
        vbase = (const short*)vT + (size_t)(b*4 + hd)*(32*NMT*2*512);
    } else {
        qbase = (const short*)qA + (size_t)b*128*NKS*512;
        kbase = (const short*)kA + (size_t)b*128*NKS*512;
        vbase = (const short*)vT + (size_t)b*(32*NMT*2*512);
    }

    short8 qf[NQ][NKS];
    #pragma unroll
    for (int qq = 0; qq < NQ; ++qq)
        #pragma unroll
        for (int ks = 0; ks < NKS; ++ks)
            qf[qq][ks] = *(const short8*)(qbase + ((size_t)(qb*NQ + qq)*NKS + ks)*512 + lane8);

    f32x4 acc[NQ][NMT];
    #pragma unroll
    for (int qq = 0; qq < NQ; ++qq)
        #pragma unroll
        for (int mt = 0; mt < NMT; ++mt) acc[qq][mt] = f32x4{0.f, 0.f, 0.f, 0.f};
    float l_lane[NQ];
    #pragma unroll
    for (int qq = 0; qq < NQ; ++qq) l_lane[qq] = 0.f;

    const int srcA = n16 + ((q4 & 1) * 2) * 16;
    const int srcB = srcA + 16;
    const bool selhi = (q4 >= 2);

    for (int kt0 = 0; kt0 < ITERS; ++kt0) {
        const int kt = ((MODE == 1) ? ksp * (NN/64/KSP) : 0) + wave * ITERS + kt0;

        if constexpr (MODE == 0) {
            // ---- straight body (r8, proven for MODE0)
            unsigned w0v[NQ][4], w1v[NQ][4];
            #pragma unroll
            for (int mt = 0; mt < 4; ++mt) {
                f32x4 c[NQ];
                #pragma unroll
                for (int qq = 0; qq < NQ; ++qq) c[qq] = f32x4{0.f, 0.f, 0.f, 0.f};
                #pragma unroll
                for (int ks = 0; ks < NKS; ++ks) {
                    short8 kf = *(const short8*)(kbase + ((size_t)(kt*4 + mt)*NKS + ks)*512 + lane8);
                    #pragma unroll
                    for (int qq = 0; qq < NQ; ++qq)
                        c[qq] = __builtin_amdgcn_mfma_f32_16x16x32_bf16(kf, qf[qq][ks], c[qq], 0, 0, 0);
                }
                #pragma unroll
                for (int qq = 0; qq < NQ; ++qq) {
                    #pragma unroll
                    for (int r = 0; r < 4; ++r) {
                        float p = __expf(c[qq][r] * scale);
                        c[qq][r] = p;
                        l_lane[qq] += p;
                    }
                    w0v[qq][mt] = bfbits(c[qq][0]) | (bfbits(c[qq][1]) << 16);
                    w1v[qq][mt] = bfbits(c[qq][2]) | (bfbits(c[qq][3]) << 16);
                }
            }
            #pragma unroll
            for (int ks2 = 0; ks2 < 2; ++ks2) {
                const int t0 = ks2*2, t1 = ks2*2 + 1;
                short8 pf[NQ];
                #pragma unroll
                for (int qq = 0; qq < NQ; ++qq) {
                    int4v pw;
                    { unsigned a = __shfl(w0v[qq][t0], srcA), bx = __shfl(w0v[qq][t1], srcA);
                      pw.x = selhi ? (int)bx : (int)a; }
                    { unsigned a = __shfl(w1v[qq][t0], srcA), bx = __shfl(w1v[qq][t1], srcA);
                      pw.y = selhi ? (int)bx : (int)a; }
                    { unsigned a = __shfl(w0v[qq][t0], srcB), bx = __shfl(w0v[qq][t1], srcB);
                      pw.z = selhi ? (int)bx : (int)a; }
                    { unsigned a = __shfl(w1v[qq][t0], srcB), bx = __shfl(w1v[qq][t1], srcB);
                      pw.w = selhi ? (int)bx : (int)a; }
                    pf[qq] = __builtin_bit_cast(short8, pw);
                }
                #pragma unroll
                for (int mt = 0; mt < NMT; ++mt) {
                    short8 vf = *(const short8*)(vbase + (((size_t)kt*NMT + mt)*2 + ks2)*512 + lane8);
                    #pragma unroll
                    for (int qq = 0; qq < NQ; ++qq)
                        acc[qq][mt] = __builtin_amdgcn_mfma_f32_16x16x32_bf16(vf, pf[qq], acc[qq][mt], 0, 0, 0);
                }
            }
        } else {
            // ---- interleaved halves (caps transient VGPRs for NQ=4)
            #pragma unroll
            for (int hh = 0; hh < 2; ++hh) {
                unsigned w0v[NQ][2], w1v[NQ][2];
                #pragma unroll
                for (int m2 = 0; m2 < 2; ++m2) {
                    const int mt = hh*2 + m2;
                    f32x4 c[NQ];
                    #pragma unroll
                    for (int qq = 0; qq < NQ; ++qq) c[qq] = f32x4{0.f, 0.f, 0.f, 0.f};
                    #pragma unroll
                    for (int ks = 0; ks < NKS; ++ks) {
                        short8 kf = *(const short8*)(kbase + ((size_t)(kt*4 + mt)*NKS + ks)*512 + lane8);
                        #pragma unroll
                        for (int qq = 0; qq < NQ; ++qq)
                            c[qq] = __builtin_amdgcn_mfma_f32_16x16x32_bf16(kf, qf[qq][ks], c[qq], 0, 0, 0);
                    }
                    #pragma unroll
                    for (int qq = 0; qq < NQ; ++qq) {
                        #pragma unroll
                        for (int r = 0; r < 4; ++r) {
                            float p = __expf(c[qq][r] * scale);
                            c[qq][r] = p;
                            l_lane[qq] += p;
                        }
                        w0v[qq][m2] = bfbits(c[qq][0]) | (bfbits(c[qq][1]) << 16);
                        w1v[qq][m2] = bfbits(c[qq][2]) | (bfbits(c[qq][3]) << 16);
                    }
                }
                short8 pf[NQ];
                #pragma unroll
                for (int qq = 0; qq < NQ; ++qq) {
                    int4v pw;
                    { unsigned a = __shfl(w0v[qq][0], srcA), bx = __shfl(w0v[qq][1], srcA);
                      pw.x = selhi ? (int)bx : (int)a; }
                    { unsigned a = __shfl(w1v[qq][0], srcA), bx = __shfl(w1v[qq][1], srcA);
                      pw.y = selhi ? (int)bx : (int)a; }
                    { unsigned a = __shfl(w0v[qq][0], srcB), bx = __shfl(w0v[qq][1], srcB);
                      pw.z = selhi ? (int)bx : (int)a; }
                    { unsigned a = __shfl(w1v[qq][0], srcB), bx = __shfl(w1v[qq][1], srcB);
                      pw.w = selhi ? (int)bx : (int)a; }
                    pf[qq] = __builtin_bit_cast(short8, pw);
                }
                #pragma unroll
                for (int mt = 0; mt < NMT; ++mt) {
                    short8 vf = *(const short8*)(vbase + (((size_t)kt*NMT + mt)*2 + hh)*512 + lane8);
                    #pragma unroll
                    for (int qq = 0; qq < NQ; ++qq)
                        acc[qq][mt] = __builtin_amdgcn_mfma_f32_16x16x32_bf16(vf, pf[qq], acc[qq][mt], 0, 0, 0);
                }
            }
        }
    }

    // ---- finalize partial denominators: reduce across q4 groups
    #pragma unroll
    for (int qq = 0; qq < NQ; ++qq) {
        l_lane[qq] += __shfl_xor(l_lane[qq], 16);
        l_lane[qq] += __shfl_xor(l_lane[qq], 32);
        if (q4 == 0) lbuf[wave][qq*16 + n16] = l_lane[qq];
    }

    // ---- publish O^T partials
    if (MODE == 0) {
        float (&oSf)[NW][NQ*16][D + 1] = *reinterpret_cast<float (*)[NW][NQ*16][D + 1]>(oS_raw);
        #pragma unroll
        for (int qq = 0; qq < NQ; ++qq)
            #pragma unroll
            for (int mt = 0; mt < NMT; ++mt)
                #pragma unroll
                for (int r = 0; r < 4; ++r)
                    oSf[wave][qq*16 + n16][mt*16 + q4*4 + r] = acc[qq][mt][r];
    } else {
        unsigned short (&oSh)[NW][NQ*16][D + 2] =
            *reinterpret_cast<unsigned short (*)[NW][NQ*16][D + 2]>(oS_raw);
        #pragma unroll
        for (int qq = 0; qq < NQ; ++qq)
            #pragma unroll
            for (int mt = 0; mt < NMT; ++mt)
                #pragma unroll
                for (int r = 0; r < 4; ++r)
                    oSh[wave][qq*16 + n16][mt*16 + q4*4 + r] = (unsigned short)bfbits(acc[qq][mt][r]);
    }
    __syncthreads();  // single barrier: merge reads all splits

    if (MODE == 0) {
        // merge + ReLU per q-tile (r8 path, unchanged)
        float (&oSf)[NW][NQ*16][D + 1] = *reinterpret_cast<float (*)[NW][NQ*16][D + 1]>(oS_raw);
        if (wave < 4) {
            const int ql = (wave & 3)*4 + (lane >> 4);
            const int d2 = (lane & 15)*2;
            #pragma unroll
            for (int qq = 0; qq < NQ; ++qq) {
                const int row = qq*16 + ql;
                float denom = 0.f, o0 = 0.f, o1 = 0.f;
                #pragma unroll
                for (int s = 0; s < NW; ++s) {
                    denom += lbuf[s][row];
                    o0 += oSf[s][row][d2];
                    o1 += oSf[s][row][d2 + 1];
                }
                float di = 1.f / denom;
                unsigned w = bfbits(fmaxf(o0*di, 0.f)) | (bfbits(fmaxf(o1*di, 0.f)) << 16);
                *(unsigned*)&hout[((size_t)b*NN + q0 + row)*DOUT + hd*32 + d2] = w;
            }
        }
    } else {
        // ksplit partial write: sum waves' O' (bf16) + denom, store UNDIVIDED.
        // P layout: [ksp][unit=b*32+qb][row 64][dim 128] bf16; D: [ksp][unit][row] f32.
        unsigned short (&oSh)[NW][NQ*16][D + 2] =
            *reinterpret_cast<unsigned short (*)[NW][NQ*16][D + 2]>(oS_raw);
        const int unit = b*32 + qb;
        const int ql = wave*4 + (lane >> 4);   // 0..15 (NW=4)
        const int d8 = (lane & 15)*8;
        #pragma unroll
        for (int qq = 0; qq < NQ; ++qq) {
            const int row = qq*16 + ql;
            float denom = 0.f;
            #pragma unroll
            for (int s = 0; s < NW; ++s) denom += lbuf[s][row];
            unsigned pk[4];
            #pragma unroll
            for (int c2 = 0; c2 < 4; ++c2) {
                float o0 = 0.f, o1 = 0.f;
                #pragma unroll
                for (int s = 0; s < NW; ++s) {
                    o0 += __uint_as_float(((unsigned)oSh[s][row][d8 + c2*2]) << 16);
                    o1 += __uint_as_float(((unsigned)oSh[s][row][d8 + c2*2 + 1]) << 16);
                }
                pk[c2] = bfbits(o0) | (bfbits(o1) << 16);
            }
            int4v pv; pv.x = (int)pk[0]; pv.y = (int)pk[1]; pv.z = (int)pk[2]; pv.w = (int)pk[3];
            *(int4v*)&hout[(((size_t)ksp*128 + unit)*64 + row)*128 + d8] = pv;
            if (d8 == 0) dout[((size_t)ksp*128 + unit)*64 + row] = denom;
        }
    }
}

// ---------------- merge: sum ksplit partials, divide, +proj residual, LayerNorm ----------------
__global__ __launch_bounds__(512) void k_merge_ln(
    const bf16* __restrict__ P, const float* __restrict__ Dn,
    const float* __restrict__ proj, const float* __restrict__ lng, const float* __restrict__ lnb,
    float* __restrict__ fout)
{
    const int u = blockIdx.x;           // 0..127 = b*32+qb
    const int b = u >> 5, qb = u & 31;
    const int q0 = qb * 64;
    const int wave = threadIdx.x >> 6, lane = threadIdx.x & 63;
    const int ql = wave*2 + (lane >> 5);  // 0..15
    const int il = lane & 31;
    #pragma unroll
    for (int qq = 0; qq < 4; ++qq) {
        const int row = qq*16 + ql;
        float denom = 0.f;
        #pragma unroll
        for (int s = 0; s < 4; ++s) denom += Dn[((size_t)s*128 + u)*64 + row];
        float di = 1.f / denom;
        size_t base = ((size_t)b*NN + q0 + row)*DOUT + il*4;
        float4 pr = *(const float4*)(proj + base);
        float y[4];
        #pragma unroll
        for (int c = 0; c < 4; ++c) {
            float o = 0.f;
            #pragma unroll
            for (int s = 0; s < 4; ++s)
                o += bf2f(P[(((size_t)s*128 + u)*64 + row)*128 + il*4 + c]);
            y[c] = o*di + ((const float*)&pr)[c];
        }
        float ssum = y[0] + y[1] + y[2] + y[3];
        #pragma unroll
        for (int off = 16; off >= 1; off >>= 1) ssum += __shfl_xor(ssum, off);
        float mu = ssum * (1.f/128.f);
        float vs = 0.f;
        #pragma unroll
        for (int c = 0; c < 4; ++c) { float d = y[c] - mu; vs += d*d; }
        #pragma unroll
        for (int off = 16; off >= 1; off >>= 1) vs += __shfl_xor(vs, off);
        float rs = rsqrtf(vs * (1.f/128.f) + 1e-3f);
        float4 g4 = *(const float4*)(lng + il*4);
        float4 b4 = *(const float4*)(lnb + il*4);
        float4 o4;
        #pragma unroll
        for (int c = 0; c < 4; ++c) {
            float o = (y[c] - mu)*rs*((const float*)&g4)[c] + ((const float*)&b4)[c];
            if (!(o == o)) o = 12345.0f;  // NaN sentinel (never hit on a passing run)
            ((float*)&o4)[c] = o;
        }
        *(float4*)(fout + base) = o4;
    }
}

extern "C" void kernel_launch(void* const* d_in, const int* in_sizes, int n_in,
                              void* d_out, int out_size, void* d_ws, size_t ws_size,
                              hipStream_t stream)
{
    const float* x   = (const float*)d_in[0];
    // d_in[1] = emb is dead: adj = sigmoid(l2norm(emb)@l2norm(emb)^T) in [0.27,1],
    // diag forced 1 -> adj==0 never true -> dense attention.
    const float* q1w = (const float*)d_in[2];
    const float* q1b = (const float*)d_in[3];
    const float* k1w = (const float*)d_in[4];
    const float* k1b = (const float*)d_in[5];
    const float* v1w = (const float*)d_in[6];
    const float* v1b = (const float*)d_in[7];
    const float* q2w = (const float*)d_in[8];
    const float* q2b = (const float*)d_in[9];
    const float* k2w = (const float*)d_in[10];
    const float* k2b = (const float*)d_in[11];
    const float* v2w = (const float*)d_in[12];
    const float* v2b = (const float*)d_in[13];
    const float* pw  = (const float*)d_in[14];
    const float* lng = (const float*)d_in[15];
    const float* lnb = (const float*)d_in[16];

    // Workspace ~20.2 MB (the harness fill of 268MB indicates d_ws is large).
    const size_t SZ = (size_t)NB*NN*DOUT;           // 1,048,576 elements
    char* wsb = (char*)d_ws;
    bf16*  qA   = (bf16*)(wsb + 0*SZ*2);            // [0,2) MB  fragment-linear
    bf16*  kA   = (bf16*)(wsb + 1*SZ*2);            // [2,4) MB
    bf16*  vT   = (bf16*)(wsb + 2*SZ*2);            // [4,6) MB
    float* proj = (float*)(wsb + 3*SZ*2);           // [6,10) MB
    bf16*  h    = (bf16*)(wsb + 3*SZ*2 + SZ*4);     // [10,12) MB
    bf16*  P    = (bf16*)(wsb + (size_t)12*1024*1024);          // [12,20) MB: 4 splits x 2MB
    float* Dn   = (float*)(wsb + (size_t)20*1024*1024);         // [20,20.125) MB

    k_gemm1<<<dim3(128, 8), 256, 0, stream>>>(x, q1w, q1b, k1w, k1b, v1w, v1b, pw,
                                              qA, kA, vT, proj);
    // MODE0: NQ=4, NW=8 -> 512 blocks, 512 threads (r8 proven)
    k_attn_mfma<32, 0, 8, 4><<<dim3(32, 16), 512, 0, stream>>>(
        qA, kA, vT, nullptr, nullptr, nullptr, h, nullptr, nullptr);
    k_gemm2<<<dim3(128, 6), 256, 0, stream>>>(h, q2w, q2b, k2w, k2b, v2w, v2b,
                                              qA, kA, vT);
    // MODE1: NQ=4, NW=4, KSPLIT=4 -> 512 blocks, 256 threads; partials to P/Dn
    k_attn_mfma<128, 1, 4, 4><<<dim3(64, 8), 256, 0, stream>>>(
        qA, kA, vT, nullptr, nullptr, nullptr, P, nullptr, Dn);
    // merge + residual + LayerNorm
    k_merge_ln<<<dim3(128), 512, 0, stream>>>(P, Dn, proj, lng, lnb, (float*)d_out);
}

// Round 10
// 199.248 us; speedup vs baseline: 1.0355x; 1.0355x over previous
//
#include <hip/hip_runtime.h>
#include <hip/hip_bf16.h>

#define NB 4
#define NN 2048
#define FIN 64
#define DOUT 128

typedef __hip_bfloat16 bf16;
typedef __attribute__((ext_vector_type(8))) short short8;
typedef __attribute__((ext_vector_type(4))) float f32x4;
typedef __attribute__((ext_vector_type(4))) int int4v;

static __device__ __forceinline__ float bf2f(bf16 v) { return __bfloat162float(v); }
static __device__ __forceinline__ bf16  f2bf(float v) { return __float2bfloat16(v); }
static __device__ __forceinline__ unsigned bfbits(float v) {
    bf16 h = __float2bfloat16(v);
    return (unsigned)*reinterpret_cast<unsigned short*>(&h);
}

// ---------------- R8 fragment-linear operand layouts (kept) ----------------
// Layer1 (H=4, D=32):  qA/kA: [(b*4+hd)][t16][lane][8];  vT: [(b*4+hd)][kt][mt][ks2][lane][8]
// Layer2 (H=1, D=128): qA/kA: [b][t16][ks][lane][8];     vT: [b][kt][mt 0..7][ks2][lane][8]

// ---------------- R10 control block (in d_ws):
// ctrl[0..511]   : claim flags, attn1 items (512)
// ctrl[512..767] : claim flags, attn2 items (256)
// ctrl[768..775] : per-XCD seq counters, attn1
// ctrl[776..783] : per-XCD seq counters, attn2
// Zeroed by k_gemm1 block (0,0) each iteration (runs before both attn kernels).

// ---------------- Kernel 1: q1,k1,vT (bf16 fragment-linear), proj (fp32) ----------------
__global__ __launch_bounds__(256) void k_gemm1(
    const float* __restrict__ x,
    const float* __restrict__ q1w, const float* __restrict__ q1b,
    const float* __restrict__ k1w, const float* __restrict__ k1b,
    const float* __restrict__ v1w, const float* __restrict__ v1b,
    const float* __restrict__ pw,
    bf16* __restrict__ qA, bf16* __restrict__ kA, bf16* __restrict__ vT,
    float* __restrict__ proj, int* __restrict__ ctrl)
{
    // zero the attn work-claim control block (before attn kernels run)
    if (blockIdx.x == 0 && blockIdx.y == 0) {
        for (int e = threadIdx.x; e < 784; e += 256) ctrl[e] = 0;
    }
    __shared__ float At[64][65];
    __shared__ float Wt[64][65];
    const int rb = blockIdx.x;
    const int cb = blockIdx.y;
    const int mat = cb >> 1;
    const int c0 = (cb & 1) * 64;
    const float* W    = (mat==0)? q1w : (mat==1)? k1w : (mat==2)? v1w : pw;
    const float* bias = (mat==0)? q1b : (mat==1)? k1b : (mat==2)? v1b : nullptr;
    const int t = threadIdx.x;
    const int row0 = rb * 64;
    for (int e = t; e < 1024; e += 256) {
        int r = e >> 4, c4 = e & 15;
        *(float4*)&At[r][c4*4] = *(const float4*)&x[(size_t)(row0 + r)*FIN + c4*4];
        *(float4*)&Wt[r][c4*4] = *(const float4*)&W[(size_t)r*DOUT + c0 + c4*4];
    }
    __syncthreads();
    const int ty = t >> 4, tx = t & 15;
    float acc[4][4] = {};
    #pragma unroll 8
    for (int k = 0; k < 64; ++k) {
        float av[4], bv[4];
        #pragma unroll
        for (int i = 0; i < 4; ++i) av[i] = At[ty*4+i][k];
        #pragma unroll
        for (int j = 0; j < 4; ++j) bv[j] = Wt[k][tx*4+j];
        #pragma unroll
        for (int i = 0; i < 4; ++i)
            #pragma unroll
            for (int j = 0; j < 4; ++j)
                acc[i][j] = fmaf(av[i], bv[j], acc[i][j]);
    }
    #pragma unroll
    for (int i = 0; i < 4; ++i) {
        int gr = row0 + ty*4 + i;
        int b = gr >> 11, n = gr & 2047;
        #pragma unroll
        for (int j = 0; j < 4; ++j) {
            int gc = c0 + tx*4 + j;
            float v = acc[i][j] + (bias ? bias[gc] : 0.f);
            if (mat == 3) { proj[(size_t)gr*DOUT + gc] = v; continue; }
            int hd = gc >> 5, d32 = gc & 31;
            if (mat == 2) {
                int kt = n >> 6, ks2 = (n >> 5) & 1, q4k = (n >> 3) & 3, jk = n & 7;
                int mt = d32 >> 4, n16d = d32 & 15;
                size_t idx = ((((size_t)(b*4+hd)*32 + kt)*2 + mt)*2 + ks2)*512
                             + (size_t)(q4k*16 + n16d)*8 + jk;
                vT[idx] = f2bf(v);
            } else {
                size_t idx = ((size_t)(b*4+hd)*128 + (n >> 4))*512
                             + (size_t)((d32 >> 3)*16 + (n & 15))*8 + (d32 & 7);
                if (mat == 0) qA[idx] = f2bf(v); else kA[idx] = f2bf(v);
            }
        }
    }
}

// ---------------- Kernel 3: q2,k2,vT (fragment-linear layer2) = h @ W (+bias) ----------------
__global__ __launch_bounds__(256) void k_gemm2(
    const bf16* __restrict__ h,
    const float* __restrict__ q2w, const float* __restrict__ q2b,
    const float* __restrict__ k2w, const float* __restrict__ k2b,
    const float* __restrict__ v2w, const float* __restrict__ v2b,
    bf16* __restrict__ qA, bf16* __restrict__ kA, bf16* __restrict__ vT)
{
    __shared__ float At[64][65];
    __shared__ float Wt[64][65];
    const int rb = blockIdx.x, cb = blockIdx.y;
    const int mat = cb >> 1, c0 = (cb & 1)*64;
    const float* W    = (mat==0)? q2w : (mat==1)? k2w : v2w;
    const float* bias = (mat==0)? q2b : (mat==1)? k2b : v2b;
    const int t = threadIdx.x, ty = t >> 4, tx = t & 15, row0 = rb*64;
    float acc[4][4] = {};
    for (int kc = 0; kc < 2; ++kc) {
        __syncthreads();
        for (int e = t; e < 512; e += 256) {
            int r = e >> 3, c8 = e & 7;
            short8 hv = *(const short8*)&h[(size_t)(row0+r)*DOUT + kc*64 + c8*8];
            #pragma unroll
            for (int u = 0; u < 8; ++u)
                At[r][c8*8 + u] = __uint_as_float(((unsigned)(unsigned short)hv[u]) << 16);
        }
        for (int e = t; e < 1024; e += 256) {
            int r = e >> 4, c4 = e & 15;
            *(float4*)&Wt[r][c4*4] = *(const float4*)&W[(size_t)(kc*64+r)*DOUT + c0 + c4*4];
        }
        __syncthreads();
        #pragma unroll 8
        for (int k = 0; k < 64; ++k) {
            float av[4], bv[4];
            #pragma unroll
            for (int i = 0; i < 4; ++i) av[i] = At[ty*4+i][k];
            #pragma unroll
            for (int j = 0; j < 4; ++j) bv[j] = Wt[k][tx*4+j];
            #pragma unroll
            for (int i = 0; i < 4; ++i)
                #pragma unroll
                for (int j = 0; j < 4; ++j)
                    acc[i][j] = fmaf(av[i], bv[j], acc[i][j]);
        }
    }
    #pragma unroll
    for (int i = 0; i < 4; ++i) {
        int gr = row0 + ty*4 + i;
        int b = gr >> 11, n = gr & 2047;
        #pragma unroll
        for (int j = 0; j < 4; ++j) {
            int gc = c0 + tx*4 + j;
            float v = acc[i][j] + bias[gc];
            if (mat == 2) {
                int kt = n >> 6, ks2 = (n >> 5) & 1, q4k = (n >> 3) & 3, jk = n & 7;
                int mt = gc >> 4, n16d = gc & 15;
                size_t idx = (((size_t)b*32 + kt)*8 + mt)*1024 + (size_t)ks2*512
                             + (size_t)(q4k*16 + n16d)*8 + jk;
                vT[idx] = f2bf(v);
            } else {
                int ks = gc >> 5, q4 = (gc >> 3) & 3, jj = gc & 7;
                size_t idx = ((size_t)b*128 + (n >> 4))*2048 + (size_t)ks*512
                             + (size_t)(q4*16 + (n & 15))*8 + jj;
                if (mat == 0) qA[idx] = f2bf(v); else kA[idx] = f2bf(v);
            }
        }
    }
}

// ---------------- MFMA flash attention v10: physical-XCD work claiming ----------------
// r9 insight: attn always ran at ~6.4-7.8 TB/s = L3 rate, never L2 (34.5). The r1
// static swizzle ASSUMED xcd = wg%8 and was neutral -> assumption likely wrong, so
// same-batch blocks never co-located and every XCD's working set (~6MB) thrashed
// its 4MB L2. R10: each block reads its REAL XCD via s_getreg(HW_REG_XCC_ID)
// (m09-verified) and claims a work item with own-XCD affinity: per-XCD atomicAdd
// seq + atomicCAS ring (exactly-once, dispatch-order-independent, no spinning).
// MODE 0: NQ=4,NW=8 (r8). MODE 1: NQ=2,NW=8 (r8 revert; 128-VGPR compiler cap
// makes NQ=4@D=128 unreachable - spilled 3x).
template<int D, int MODE, int NW, int NQ>
__global__ __launch_bounds__(NW*64, 2) void k_attn_mfma(
    const bf16* __restrict__ qA, const bf16* __restrict__ kA, const bf16* __restrict__ vT,
    const float* __restrict__ proj, const float* __restrict__ lng, const float* __restrict__ lnb,
    bf16* __restrict__ hout, float* __restrict__ fout, int* __restrict__ ctrl)
{
    constexpr int NKS = D / 32;     // 32-dim k-steps in S^T
    constexpr int NMT = D / 16;     // 16-dim m-tiles of O^T
    constexpr int ITERS = NN / (64 * NW);
    constexpr int NITEMS = (MODE == 0) ? 512 : 256;

    __shared__ float lbuf[NW][NQ*16];
    __shared__ int s_item;
    constexpr int OSW = (MODE == 0) ? (D + 1) : (D + 2);
    __shared__ char oS_raw[(size_t)NW * NQ*16 * OSW * ((MODE == 0) ? 4 : 2)];

    const float scale = (D == 32) ? 0.17677669529663687f : 0.08838834764831843f;

    // ---- claim a work item with own-XCD affinity
    if (threadIdx.x == 0) {
        unsigned xcc;
        asm volatile("s_getreg_b32 %0, hwreg(HW_REG_XCC_ID)" : "=s"(xcc));
        xcc &= 7u;
        int* claim = ctrl + ((MODE == 0) ? 0 : 512);
        int* ctr   = ctrl + ((MODE == 0) ? 768 : 776);
        // preferred start: own XCD's contiguous chunk of items
        int start;
        if constexpr (MODE == 0) start = (int)xcc * 64;             // bh {2x,2x+1}
        else                     start = (int)(xcc >> 1) * 64 + (int)(xcc & 1) * 32;
        int seq = atomicAdd(&ctr[xcc], 1);
        int item = -1;
        for (int a = 0; a < NITEMS; ++a) {
            int it = (start + seq + a) & (NITEMS - 1);
            if (atomicCAS(&claim[it], 0, 1) == 0) { item = it; break; }
        }
        s_item = item;
    }
    __syncthreads();
    const int item = s_item;

    int b, hd, qb;
    if constexpr (MODE == 0) {
        int bh = item >> 5; qb = item & 31;      // 512 items: 16 bh x 32 qb
        b = bh >> 2; hd = bh & 3;
    } else {
        b = item >> 6; qb = item & 63; hd = 0;   // 256 items: 4 b x 64 qb
    }

    const int q0 = qb * (16*NQ);
    const int wave = threadIdx.x >> 6, lane = threadIdx.x & 63;
    const int n16 = lane & 15, q4 = lane >> 4;
    const int lane8 = lane * 8;

    // fragment-linear bases
    const short* qbase, * kbase, * vbase;
    if constexpr (MODE == 0) {
        qbase = (const short*)qA + (size_t)(b*4 + hd)*128*512;
        kbase = (const short*)kA + (size_t)(b*4 + hd)*128*512;
        vbase = (const short*)vT + (size_t)(b*4 + hd)*(32*NMT*2*512);
    } else {
        qbase = (const short*)qA + (size_t)b*128*NKS*512;
        kbase = (const short*)kA + (size_t)b*128*NKS*512;
        vbase = (const short*)vT + (size_t)b*(32*NMT*2*512);
    }

    short8 qf[NQ][NKS];
    #pragma unroll
    for (int qq = 0; qq < NQ; ++qq)
        #pragma unroll
        for (int ks = 0; ks < NKS; ++ks)
            qf[qq][ks] = *(const short8*)(qbase + ((size_t)(qb*NQ + qq)*NKS + ks)*512 + lane8);

    f32x4 acc[NQ][NMT];
    #pragma unroll
    for (int qq = 0; qq < NQ; ++qq)
        #pragma unroll
        for (int mt = 0; mt < NMT; ++mt) acc[qq][mt] = f32x4{0.f, 0.f, 0.f, 0.f};
    float l_lane[NQ];
    #pragma unroll
    for (int qq = 0; qq < NQ; ++qq) l_lane[qq] = 0.f;

    const int srcA = n16 + ((q4 & 1) * 2) * 16;
    const int srcB = srcA + 16;
    const bool selhi = (q4 >= 2);

    for (int kt0 = 0; kt0 < ITERS; ++kt0) {
        const int kt = wave * ITERS + kt0;     // this wave's key chunk (64 keys)

        unsigned w0v[NQ][4], w1v[NQ][4];
        #pragma unroll
        for (int mt = 0; mt < 4; ++mt) {
            f32x4 c[NQ];
            #pragma unroll
            for (int qq = 0; qq < NQ; ++qq) c[qq] = f32x4{0.f, 0.f, 0.f, 0.f};
            #pragma unroll
            for (int ks = 0; ks < NKS; ++ks) {
                short8 kf = *(const short8*)(kbase + ((size_t)(kt*4 + mt)*NKS + ks)*512 + lane8);
                #pragma unroll
                for (int qq = 0; qq < NQ; ++qq)
                    c[qq] = __builtin_amdgcn_mfma_f32_16x16x32_bf16(kf, qf[qq][ks], c[qq], 0, 0, 0);
            }
            #pragma unroll
            for (int qq = 0; qq < NQ; ++qq) {
                #pragma unroll
                for (int r = 0; r < 4; ++r) {
                    float p = __expf(c[qq][r] * scale);
                    c[qq][r] = p;
                    l_lane[qq] += p;
                }
                w0v[qq][mt] = bfbits(c[qq][0]) | (bfbits(c[qq][1]) << 16);
                w1v[qq][mt] = bfbits(c[qq][2]) | (bfbits(c[qq][3]) << 16);
            }
        }
        #pragma unroll
        for (int ks2 = 0; ks2 < 2; ++ks2) {
            const int t0 = ks2*2, t1 = ks2*2 + 1;
            short8 pf[NQ];
            #pragma unroll
            for (int qq = 0; qq < NQ; ++qq) {
                int4v pw;
                { unsigned a = __shfl(w0v[qq][t0], srcA), bx = __shfl(w0v[qq][t1], srcA);
                  pw.x = selhi ? (int)bx : (int)a; }
                { unsigned a = __shfl(w1v[qq][t0], srcA), bx = __shfl(w1v[qq][t1], srcA);
                  pw.y = selhi ? (int)bx : (int)a; }
                { unsigned a = __shfl(w0v[qq][t0], srcB), bx = __shfl(w0v[qq][t1], srcB);
                  pw.z = selhi ? (int)bx : (int)a; }
                { unsigned a = __shfl(w1v[qq][t0], srcB), bx = __shfl(w1v[qq][t1], srcB);
                  pw.w = selhi ? (int)bx : (int)a; }
                pf[qq] = __builtin_bit_cast(short8, pw);
            }
            #pragma unroll
            for (int mt = 0; mt < NMT; ++mt) {
                short8 vf = *(const short8*)(vbase + (((size_t)kt*NMT + mt)*2 + ks2)*512 + lane8);
                #pragma unroll
                for (int qq = 0; qq < NQ; ++qq)
                    acc[qq][mt] = __builtin_amdgcn_mfma_f32_16x16x32_bf16(vf, pf[qq], acc[qq][mt], 0, 0, 0);
            }
        }
    }

    // ---- finalize denominators: reduce across q4 groups
    #pragma unroll
    for (int qq = 0; qq < NQ; ++qq) {
        l_lane[qq] += __shfl_xor(l_lane[qq], 16);
        l_lane[qq] += __shfl_xor(l_lane[qq], 32);
        if (q4 == 0) lbuf[wave][qq*16 + n16] = l_lane[qq];
    }

    // ---- publish O^T partials
    if (MODE == 0) {
        float (&oSf)[NW][NQ*16][D + 1] = *reinterpret_cast<float (*)[NW][NQ*16][D + 1]>(oS_raw);
        #pragma unroll
        for (int qq = 0; qq < NQ; ++qq)
            #pragma unroll
            for (int mt = 0; mt < NMT; ++mt)
                #pragma unroll
                for (int r = 0; r < 4; ++r)
                    oSf[wave][qq*16 + n16][mt*16 + q4*4 + r] = acc[qq][mt][r];
    } else {
        unsigned short (&oSh)[NW][NQ*16][D + 2] =
            *reinterpret_cast<unsigned short (*)[NW][NQ*16][D + 2]>(oS_raw);
        #pragma unroll
        for (int qq = 0; qq < NQ; ++qq)
            #pragma unroll
            for (int mt = 0; mt < NMT; ++mt)
                #pragma unroll
                for (int r = 0; r < 4; ++r)
                    oSh[wave][qq*16 + n16][mt*16 + q4*4 + r] = (unsigned short)bfbits(acc[qq][mt][r]);
    }
    __syncthreads();  // single barrier: merge reads all splits

    if (MODE == 0) {
        // merge + ReLU per q-tile; waves 0-3 merge
        float (&oSf)[NW][NQ*16][D + 1] = *reinterpret_cast<float (*)[NW][NQ*16][D + 1]>(oS_raw);
        if (wave < 4) {
            const int ql = (wave & 3)*4 + (lane >> 4);
            const int d2 = (lane & 15)*2;
            #pragma unroll
            for (int qq = 0; qq < NQ; ++qq) {
                const int row = qq*16 + ql;
                float denom = 0.f, o0 = 0.f, o1 = 0.f;
                #pragma unroll
                for (int s = 0; s < NW; ++s) {
                    denom += lbuf[s][row];
                    o0 += oSf[s][row][d2];
                    o1 += oSf[s][row][d2 + 1];
                }
                float di = 1.f / denom;
                unsigned w = bfbits(fmaxf(o0*di, 0.f)) | (bfbits(fmaxf(o1*di, 0.f)) << 16);
                *(unsigned*)&hout[((size_t)b*NN + q0 + row)*DOUT + hd*32 + d2] = w;
            }
        }
    } else {
        // merge + residual + LayerNorm per q-tile
        unsigned short (&oSh)[NW][NQ*16][D + 2] =
            *reinterpret_cast<unsigned short (*)[NW][NQ*16][D + 2]>(oS_raw);
        const int ql = wave*2 + (lane >> 5);
        const int il = lane & 31;
        #pragma unroll
        for (int qq = 0; qq < NQ; ++qq) {
            const int row = qq*16 + ql;
            float denom = 0.f;
            #pragma unroll
            for (int s = 0; s < NW; ++s) denom += lbuf[s][row];
            float di = 1.f / denom;
            size_t base = ((size_t)b*NN + q0 + row)*DOUT + il*4;
            float4 pr = *(const float4*)(proj + base);
            float y[4];
            #pragma unroll
            for (int c = 0; c < 4; ++c) {
                float o = 0.f;
                #pragma unroll
                for (int s = 0; s < NW; ++s)
                    o += __uint_as_float(((unsigned)oSh[s][row][il*4 + c]) << 16);
                y[c] = o*di + ((const float*)&pr)[c];
            }
            float ssum = y[0] + y[1] + y[2] + y[3];
            #pragma unroll
            for (int off = 16; off >= 1; off >>= 1) ssum += __shfl_xor(ssum, off);
            float mu = ssum * (1.f/128.f);
            float vs = 0.f;
            #pragma unroll
            for (int c = 0; c < 4; ++c) { float d = y[c] - mu; vs += d*d; }
            #pragma unroll
            for (int off = 16; off >= 1; off >>= 1) vs += __shfl_xor(vs, off);
            float rs = rsqrtf(vs * (1.f/128.f) + 1e-3f);
            float4 g4 = *(const float4*)(lng + il*4);
            float4 b4 = *(const float4*)(lnb + il*4);
            float4 o4;
            #pragma unroll
            for (int c = 0; c < 4; ++c) {
                float o = (y[c] - mu)*rs*((const float*)&g4)[c] + ((const float*)&b4)[c];
                if (!(o == o)) o = 12345.0f;  // NaN sentinel (never hit on a passing run)
                ((float*)&o4)[c] = o;
            }
            *(float4*)(fout + base) = o4;
        }
    }
}

extern "C" void kernel_launch(void* const* d_in, const int* in_sizes, int n_in,
                              void* d_out, int out_size, void* d_ws, size_t ws_size,
                              hipStream_t stream)
{
    const float* x   = (const float*)d_in[0];
    // d_in[1] = emb is dead: adj = sigmoid(l2norm(emb)@l2norm(emb)^T) in [0.27,1],
    // diag forced 1 -> adj==0 never true -> dense attention.
    const float* q1w = (const float*)d_in[2];
    const float* q1b = (const float*)d_in[3];
    const float* k1w = (const float*)d_in[4];
    const float* k1b = (const float*)d_in[5];
    const float* v1w = (const float*)d_in[6];
    const float* v1b = (const float*)d_in[7];
    const float* q2w = (const float*)d_in[8];
    const float* q2b = (const float*)d_in[9];
    const float* k2w = (const float*)d_in[10];
    const float* k2b = (const float*)d_in[11];
    const float* v2w = (const float*)d_in[12];
    const float* v2b = (const float*)d_in[13];
    const float* pw  = (const float*)d_in[14];
    const float* lng = (const float*)d_in[15];
    const float* lnb = (const float*)d_in[16];

    const size_t SZ = (size_t)NB*NN*DOUT;           // 1,048,576 elements
    char* wsb = (char*)d_ws;
    bf16*  qA   = (bf16*)(wsb + 0*SZ*2);            // [0,2) MB  fragment-linear
    bf16*  kA   = (bf16*)(wsb + 1*SZ*2);            // [2,4) MB
    bf16*  vT   = (bf16*)(wsb + 2*SZ*2);            // [4,6) MB
    float* proj = (float*)(wsb + 3*SZ*2);           // [6,10) MB
    bf16*  h    = (bf16*)(wsb + 3*SZ*2 + SZ*4);     // [10,12) MB
    int*   ctrl = (int*)(wsb + (size_t)12*1024*1024);  // [12MB, +3136B) claim/ctr

    k_gemm1<<<dim3(128, 8), 256, 0, stream>>>(x, q1w, q1b, k1w, k1b, v1w, v1b, pw,
                                              qA, kA, vT, proj, ctrl);
    // MODE0: NQ=4, NW=8 -> 512 blocks, 512 threads
    k_attn_mfma<32, 0, 8, 4><<<dim3(32, 16), 512, 0, stream>>>(
        qA, kA, vT, nullptr, nullptr, nullptr, h, nullptr, ctrl);
    k_gemm2<<<dim3(128, 6), 256, 0, stream>>>(h, q2w, q2b, k2w, k2b, v2w, v2b,
                                              qA, kA, vT);
    // MODE1: NQ=2, NW=8 -> 256 blocks, 512 threads (r8 proven config)
    k_attn_mfma<128, 1, 8, 2><<<dim3(64, 4), 512, 0, stream>>>(
        qA, kA, vT, proj, lng, lnb, nullptr, (float*)d_out, ctrl);
}

// Round 13
// 184.542 us; speedup vs baseline: 1.1180x; 1.0797x over previous
//
#include <hip/hip_runtime.h>
#include <hip/hip_bf16.h>

#define NB 4
#define NN 2048
#define FIN 64
#define DOUT 128

typedef __hip_bfloat16 bf16;
typedef __attribute__((ext_vector_type(8))) short short8;
typedef __attribute__((ext_vector_type(4))) float f32x4;
typedef __attribute__((ext_vector_type(4))) int int4v;

static __device__ __forceinline__ float bf2f(bf16 v) { return __bfloat162float(v); }
static __device__ __forceinline__ bf16  f2bf(float v) { return __float2bfloat16(v); }
static __device__ __forceinline__ unsigned bfbits(float v) {
    bf16 h = __float2bfloat16(v);
    return (unsigned)*reinterpret_cast<unsigned short*>(&h);
}

// ---------------- R8 fragment-linear operand layouts (kept) ----------------
// Layer1 (H=4, D=32):  qA/kA idx = ((b*4+hd)*128 + t16)*512 + (dgrp*16+n16)*8 + j
//                      vT   idx = ((((b*4+hd)*32+kt)*2+mt)*2+ks2)*512 + (q4k*16+n16d)*8 + jk
// Layer2 (H=1, D=128): qA/kA idx = (b*128+t16)*2048 + ks*512 + (q4*16+n16)*8 + jj
//                      vT   idx = ((b*32+kt)*8+mt)*1024 + ks2*512 + (q4k*16+n16d)*8 + jk
// t16/kt/n16 etc are BATCH-LOCAL (n & 2047) — the r11 bug was using global rows.
// R12/R13: gemm epilogues stage the 64x64 tile in LDS ([64][72] padded), then emit
// contiguous 16B short8 stores with lane-coalesced chunk order (consecutive
// lanes -> consecutive 16B -> 1KB/wave-instruction).

// ---------------- Kernel 1: q1,k1,vT (bf16 fragment-linear), proj (fp32) ----------------
__global__ __launch_bounds__(256) void k_gemm1(
    const float* __restrict__ x,
    const float* __restrict__ q1w, const float* __restrict__ q1b,
    const float* __restrict__ k1w, const float* __restrict__ k1b,
    const float* __restrict__ v1w, const float* __restrict__ v1b,
    const float* __restrict__ pw,
    bf16* __restrict__ qA, bf16* __restrict__ kA, bf16* __restrict__ vT,
    float* __restrict__ proj)
{
    __shared__ float At[64][65];
    __shared__ float Wt[64][65];
    __shared__ bf16  stg[64][72];    // padded: 144B row stride, 16B-aligned
    const int rb = blockIdx.x;
    const int cb = blockIdx.y;
    const int mat = cb >> 1;
    const int c0 = (cb & 1) * 64;
    const float* W    = (mat==0)? q1w : (mat==1)? k1w : (mat==2)? v1w : pw;
    const float* bias = (mat==0)? q1b : (mat==1)? k1b : (mat==2)? v1b : nullptr;
    const int t = threadIdx.x;
    const int row0 = rb * 64;
    for (int e = t; e < 1024; e += 256) {
        int r = e >> 4, c4 = e & 15;
        *(float4*)&At[r][c4*4] = *(const float4*)&x[(size_t)(row0 + r)*FIN + c4*4];
        *(float4*)&Wt[r][c4*4] = *(const float4*)&W[(size_t)r*DOUT + c0 + c4*4];
    }
    __syncthreads();
    const int ty = t >> 4, tx = t & 15;
    float acc[4][4] = {};
    #pragma unroll 8
    for (int k = 0; k < 64; ++k) {
        float av[4], bv[4];
        #pragma unroll
        for (int i = 0; i < 4; ++i) av[i] = At[ty*4+i][k];
        #pragma unroll
        for (int j = 0; j < 4; ++j) bv[j] = Wt[k][tx*4+j];
        #pragma unroll
        for (int i = 0; i < 4; ++i)
            #pragma unroll
            for (int j = 0; j < 4; ++j)
                acc[i][j] = fmaf(av[i], bv[j], acc[i][j]);
    }

    if (mat == 3) {
        // proj: contiguous float4 stores, no staging
        #pragma unroll
        for (int i = 0; i < 4; ++i) {
            int gr = row0 + ty*4 + i;
            float4 o;
            #pragma unroll
            for (int j = 0; j < 4; ++j) ((float*)&o)[j] = acc[i][j];
            *(float4*)&proj[(size_t)gr*DOUT + c0 + tx*4] = o;
        }
        return;
    }

    // stage tile (+bias) to LDS: q/k row-major [row][col]; vT transposed [col][row]
    #pragma unroll
    for (int i = 0; i < 4; ++i) {
        #pragma unroll
        for (int j = 0; j < 4; ++j) {
            int lc = tx*4 + j;
            float v = acc[i][j] + bias[c0 + lc];
            if (mat == 2) stg[lc][ty*4 + i] = f2bf(v);
            else          stg[ty*4 + i][lc] = f2bf(v);
        }
    }
    __syncthreads();

    const int b   = row0 >> 11;
    const int nb0 = row0 & 2047;      // batch-local base row (r11 bugfix)
    // 512 contiguous 16B chunks, 2 per thread; lane-coalesced order
    #pragma unroll
    for (int kk = 0; kk < 2; ++kk) {
        int e = t + kk*256;
        int n16 = e & 15, dg = (e >> 4) & 3, hh = (e >> 6) & 1, top = (e >> 7) & 3;
        if (mat == 2) {
            // vT: top=(hd_local,mt), hh=ks2, dg=q4k, n16=n16d; 8 consecutive keys
            int lc = top*16 + n16;               // dim within the 64-col block
            int hd = (c0 >> 5) + (top >> 1);
            int mt = top & 1;
            int kt = nb0 >> 6;                   // (r11 bugfix: batch-local)
            size_t base = ((((size_t)(b*4+hd)*32 + kt)*2 + mt)*2 + hh)*512
                          + (size_t)(dg*16 + n16)*8;
            short8 val = *(const short8*)&stg[lc][hh*32 + dg*8];
            *(short8*)((short*)vT + base) = val;
        } else {
            // q/k: top=row-hi, hh=head_local, dg=dim-group; 8 consecutive dims
            int lr = top*16 + n16;
            int t16 = (nb0 >> 4) + top;          // (r11 bugfix: batch-local)
            int hd = (c0 >> 5) + hh;
            size_t base = ((size_t)(b*4+hd)*128 + t16)*512 + (size_t)(dg*16 + n16)*8;
            short8 val = *(const short8*)&stg[lr][hh*32 + dg*8];
            *(short8*)((short*)(mat == 0 ? qA : kA) + base) = val;
        }
    }
}

// ---------------- Kernel 3: q2,k2,vT (fragment-linear layer2) = h @ W (+bias) ----------------
__global__ __launch_bounds__(256) void k_gemm2(
    const bf16* __restrict__ h,
    const float* __restrict__ q2w, const float* __restrict__ q2b,
    const float* __restrict__ k2w, const float* __restrict__ k2b,
    const float* __restrict__ v2w, const float* __restrict__ v2b,
    bf16* __restrict__ qA, bf16* __restrict__ kA, bf16* __restrict__ vT)
{
    __shared__ float At[64][65];
    __shared__ float Wt[64][65];
    __shared__ bf16  stg[64][72];
    const int rb = blockIdx.x, cb = blockIdx.y;
    const int mat = cb >> 1, c0 = (cb & 1)*64;
    const float* W    = (mat==0)? q2w : (mat==1)? k2w : v2w;
    const float* bias = (mat==0)? q2b : (mat==1)? k2b : v2b;
    const int t = threadIdx.x, ty = t >> 4, tx = t & 15, row0 = rb*64;
    float acc[4][4] = {};
    for (int kc = 0; kc < 2; ++kc) {
        __syncthreads();
        for (int e = t; e < 512; e += 256) {
            int r = e >> 3, c8 = e & 7;
            short8 hv = *(const short8*)&h[(size_t)(row0+r)*DOUT + kc*64 + c8*8];
            #pragma unroll
            for (int u = 0; u < 8; ++u)
                At[r][c8*8 + u] = __uint_as_float(((unsigned)(unsigned short)hv[u]) << 16);
        }
        for (int e = t; e < 1024; e += 256) {
            int r = e >> 4, c4 = e & 15;
            *(float4*)&Wt[r][c4*4] = *(const float4*)&W[(size_t)(kc*64+r)*DOUT + c0 + c4*4];
        }
        __syncthreads();
        #pragma unroll 8
        for (int k = 0; k < 64; ++k) {
            float av[4], bv[4];
            #pragma unroll
            for (int i = 0; i < 4; ++i) av[i] = At[ty*4+i][k];
            #pragma unroll
            for (int j = 0; j < 4; ++j) bv[j] = Wt[k][tx*4+j];
            #pragma unroll
            for (int i = 0; i < 4; ++i)
                #pragma unroll
                for (int j = 0; j < 4; ++j)
                    acc[i][j] = fmaf(av[i], bv[j], acc[i][j]);
        }
    }

    // stage tile (+bias): q/k row-major; vT transposed
    #pragma unroll
    for (int i = 0; i < 4; ++i) {
        #pragma unroll
        for (int j = 0; j < 4; ++j) {
            int lc = tx*4 + j;
            float v = acc[i][j] + bias[c0 + lc];
            if (mat == 2) stg[lc][ty*4 + i] = f2bf(v);
            else          stg[ty*4 + i][lc] = f2bf(v);
        }
    }
    __syncthreads();

    const int b   = row0 >> 11;
    const int nb0 = row0 & 2047;      // batch-local (r11 bugfix)
    #pragma unroll
    for (int kk = 0; kk < 2; ++kk) {
        int e = t + kk*256;
        int n16 = e & 15, dg = (e >> 4) & 3, hh = (e >> 6) & 1, top = (e >> 7) & 3;
        if (mat == 2) {
            // layer2 vT: top=mt_local, hh=ks2, dg=q4k; 8 consecutive keys
            int lc = top*16 + n16;
            int mt = (c0 >> 4) + top;
            int kt = nb0 >> 6;
            size_t base = (((size_t)b*32 + kt)*8 + mt)*1024 + (size_t)hh*512
                          + (size_t)(dg*16 + n16)*8;
            short8 val = *(const short8*)&stg[lc][hh*32 + dg*8];
            *(short8*)((short*)vT + base) = val;
        } else {
            // layer2 q/k: top=row-hi, hh=ks-half, dg=q4; 8 consecutive dims
            int lr = top*16 + n16;
            int t16 = (nb0 >> 4) + top;
            int ks = (c0 >> 5) + hh;
            size_t base = ((size_t)b*128 + t16)*2048 + (size_t)ks*512
                          + (size_t)(dg*16 + n16)*8;
            short8 val = *(const short8*)&stg[lr][hh*32 + dg*8];
            *(short8*)((short*)(mat == 0 ? qA : kA) + base) = val;
        }
    }
}

// ---------------- MFMA flash attention (r8 proven config, static swizzle) ----------------
// Established model (r1/r2/r7/r8/r10 nulls + r5 hit): attn time = F(~15us) +
// bytes/6.4TB/s, placement- and pattern-invariant. MODE 0: NQ=4,NW=8.
// MODE 1: NQ=2,NW=8 (128-VGPR compiler cap blocks NQ=4@D=128 — spilled 3x).
template<int D, int MODE, int NW, int NQ>
__global__ __launch_bounds__(NW*64, 2) void k_attn_mfma(
    const bf16* __restrict__ qA, const bf16* __restrict__ kA, const bf16* __restrict__ vT,
    const float* __restrict__ proj, const float* __restrict__ lng, const float* __restrict__ lnb,
    bf16* __restrict__ hout, float* __restrict__ fout)
{
    constexpr int NKS = D / 32;
    constexpr int NMT = D / 16;
    constexpr int ITERS = NN / (64 * NW);

    __shared__ float lbuf[NW][NQ*16];
    constexpr int OSW = (MODE == 0) ? (D + 1) : (D + 2);
    __shared__ char oS_raw[(size_t)NW * NQ*16 * OSW * ((MODE == 0) ? 4 : 2)];

    const float scale = (D == 32) ? 0.17677669529663687f : 0.08838834764831843f;

    const unsigned wg  = blockIdx.x + (unsigned)gridDim.x * blockIdx.y;
    const unsigned xcd = wg & 7u;
    const unsigned idx = wg >> 3;
    int qb, bh;
    if constexpr (MODE == 0) {
        bh = (int)((xcd << 1) | (idx >> 5));   // 0..15
        qb = (int)(idx & 31u);                 // 0..31
    } else {
        bh = (int)(xcd >> 1);                  // 0..3
        qb = (int)(((xcd & 1u) << 5) | idx);   // 0..63
    }

    const int b  = (MODE == 0) ? (bh >> 2) : bh;
    const int hd = (MODE == 0) ? (bh & 3) : 0;
    const int q0 = qb * (16*NQ);
    const int wave = threadIdx.x >> 6, lane = threadIdx.x & 63;
    const int n16 = lane & 15, q4 = lane >> 4;
    const int lane8 = lane * 8;

    const short* qbase, * kbase, * vbase;
    if constexpr (MODE == 0) {
        qbase = (const short*)qA + (size_t)(b*4 + hd)*128*512;
        kbase = (const short*)kA + (size_t)(b*4 + hd)*128*512;
        vbase = (const short*)vT + (size_t)(b*4 + hd)*(32*NMT*2*512);
    } else {
        qbase = (const short*)qA + (size_t)b*128*NKS*512;
        kbase = (const short*)kA + (size_t)b*128*NKS*512;
        vbase = (const short*)vT + (size_t)b*(32*NMT*2*512);
    }

    short8 qf[NQ][NKS];
    #pragma unroll
    for (int qq = 0; qq < NQ; ++qq)
        #pragma unroll
        for (int ks = 0; ks < NKS; ++ks)
            qf[qq][ks] = *(const short8*)(qbase + ((size_t)(qb*NQ + qq)*NKS + ks)*512 + lane8);

    f32x4 acc[NQ][NMT];
    #pragma unroll
    for (int qq = 0; qq < NQ; ++qq)
        #pragma unroll
        for (int mt = 0; mt < NMT; ++mt) acc[qq][mt] = f32x4{0.f, 0.f, 0.f, 0.f};
    float l_lane[NQ];
    #pragma unroll
    for (int qq = 0; qq < NQ; ++qq) l_lane[qq] = 0.f;

    const int srcA = n16 + ((q4 & 1) * 2) * 16;
    const int srcB = srcA + 16;
    const bool selhi = (q4 >= 2);

    for (int kt0 = 0; kt0 < ITERS; ++kt0) {
        const int kt = wave * ITERS + kt0;

        unsigned w0v[NQ][4], w1v[NQ][4];
        #pragma unroll
        for (int mt = 0; mt < 4; ++mt) {
            f32x4 c[NQ];
            #pragma unroll
            for (int qq = 0; qq < NQ; ++qq) c[qq] = f32x4{0.f, 0.f, 0.f, 0.f};
            #pragma unroll
            for (int ks = 0; ks < NKS; ++ks) {
                short8 kf = *(const short8*)(kbase + ((size_t)(kt*4 + mt)*NKS + ks)*512 + lane8);
                #pragma unroll
                for (int qq = 0; qq < NQ; ++qq)
                    c[qq] = __builtin_amdgcn_mfma_f32_16x16x32_bf16(kf, qf[qq][ks], c[qq], 0, 0, 0);
            }
            #pragma unroll
            for (int qq = 0; qq < NQ; ++qq) {
                #pragma unroll
                for (int r = 0; r < 4; ++r) {
                    float p = __expf(c[qq][r] * scale);
                    c[qq][r] = p;
                    l_lane[qq] += p;
                }
                w0v[qq][mt] = bfbits(c[qq][0]) | (bfbits(c[qq][1]) << 16);
                w1v[qq][mt] = bfbits(c[qq][2]) | (bfbits(c[qq][3]) << 16);
            }
        }
        #pragma unroll
        for (int ks2 = 0; ks2 < 2; ++ks2) {
            const int t0 = ks2*2, t1 = ks2*2 + 1;
            short8 pf[NQ];
            #pragma unroll
            for (int qq = 0; qq < NQ; ++qq) {
                int4v pw;
                { unsigned a = __shfl(w0v[qq][t0], srcA), bx = __shfl(w0v[qq][t1], srcA);
                  pw.x = selhi ? (int)bx : (int)a; }
                { unsigned a = __shfl(w1v[qq][t0], srcA), bx = __shfl(w1v[qq][t1], srcA);
                  pw.y = selhi ? (int)bx : (int)a; }
                { unsigned a = __shfl(w0v[qq][t0], srcB), bx = __shfl(w0v[qq][t1], srcB);
                  pw.z = selhi ? (int)bx : (int)a; }
                { unsigned a = __shfl(w1v[qq][t0], srcB), bx = __shfl(w1v[qq][t1], srcB);
                  pw.w = selhi ? (int)bx : (int)a; }
                pf[qq] = __builtin_bit_cast(short8, pw);
            }
            #pragma unroll
            for (int mt = 0; mt < NMT; ++mt) {
                short8 vf = *(const short8*)(vbase + (((size_t)kt*NMT + mt)*2 + ks2)*512 + lane8);
                #pragma unroll
                for (int qq = 0; qq < NQ; ++qq)
                    acc[qq][mt] = __builtin_amdgcn_mfma_f32_16x16x32_bf16(vf, pf[qq], acc[qq][mt], 0, 0, 0);
            }
        }
    }

    #pragma unroll
    for (int qq = 0; qq < NQ; ++qq) {
        l_lane[qq] += __shfl_xor(l_lane[qq], 16);
        l_lane[qq] += __shfl_xor(l_lane[qq], 32);
        if (q4 == 0) lbuf[wave][qq*16 + n16] = l_lane[qq];
    }

    if (MODE == 0) {
        float (&oSf)[NW][NQ*16][D + 1] = *reinterpret_cast<float (*)[NW][NQ*16][D + 1]>(oS_raw);
        #pragma unroll
        for (int qq = 0; qq < NQ; ++qq)
            #pragma unroll
            for (int mt = 0; mt < NMT; ++mt)
                #pragma unroll
                for (int r = 0; r < 4; ++r)
                    oSf[wave][qq*16 + n16][mt*16 + q4*4 + r] = acc[qq][mt][r];
    } else {
        unsigned short (&oSh)[NW][NQ*16][D + 2] =
            *reinterpret_cast<unsigned short (*)[NW][NQ*16][D + 2]>(oS_raw);
        #pragma unroll
        for (int qq = 0; qq < NQ; ++qq)
            #pragma unroll
            for (int mt = 0; mt < NMT; ++mt)
                #pragma unroll
                for (int r = 0; r < 4; ++r)
                    oSh[wave][qq*16 + n16][mt*16 + q4*4 + r] = (unsigned short)bfbits(acc[qq][mt][r]);
    }
    __syncthreads();

    if (MODE == 0) {
        float (&oSf)[NW][NQ*16][D + 1] = *reinterpret_cast<float (*)[NW][NQ*16][D + 1]>(oS_raw);
        if (wave < 4) {
            const int ql = (wave & 3)*4 + (lane >> 4);
            const int d2 = (lane & 15)*2;
            #pragma unroll
            for (int qq = 0; qq < NQ; ++qq) {
                const int row = qq*16 + ql;
                float denom = 0.f, o0 = 0.f, o1 = 0.f;
                #pragma unroll
                for (int s = 0; s < NW; ++s) {
                    denom += lbuf[s][row];
                    o0 += oSf[s][row][d2];
                    o1 += oSf[s][row][d2 + 1];
                }
                float di = 1.f / denom;
                unsigned w = bfbits(fmaxf(o0*di, 0.f)) | (bfbits(fmaxf(o1*di, 0.f)) << 16);
                *(unsigned*)&hout[((size_t)b*NN + q0 + row)*DOUT + hd*32 + d2] = w;
            }
        }
    } else {
        unsigned short (&oSh)[NW][NQ*16][D + 2] =
            *reinterpret_cast<unsigned short (*)[NW][NQ*16][D + 2]>(oS_raw);
        const int ql = wave*2 + (lane >> 5);
        const int il = lane & 31;
        #pragma unroll
        for (int qq = 0; qq < NQ; ++qq) {
            const int row = qq*16 + ql;
            float denom = 0.f;
            #pragma unroll
            for (int s = 0; s < NW; ++s) denom += lbuf[s][row];
            float di = 1.f / denom;
            size_t base = ((size_t)b*NN + q0 + row)*DOUT + il*4;
            float4 pr = *(const float4*)(proj + base);
            float y[4];
            #pragma unroll
            for (int c = 0; c < 4; ++c) {
                float o = 0.f;
                #pragma unroll
                for (int s = 0; s < NW; ++s)
                    o += __uint_as_float(((unsigned)oSh[s][row][il*4 + c]) << 16);
                y[c] = o*di + ((const float*)&pr)[c];
            }
            float ssum = y[0] + y[1] + y[2] + y[3];
            #pragma unroll
            for (int off = 16; off >= 1; off >>= 1) ssum += __shfl_xor(ssum, off);
            float mu = ssum * (1.f/128.f);
            float vs = 0.f;
            #pragma unroll
            for (int c = 0; c < 4; ++c) { float d = y[c] - mu; vs += d*d; }
            #pragma unroll
            for (int off = 16; off >= 1; off >>= 1) vs += __shfl_xor(vs, off);
            float rs = rsqrtf(vs * (1.f/128.f) + 1e-3f);
            float4 g4 = *(const float4*)(lng + il*4);
            float4 b4 = *(const float4*)(lnb + il*4);
            float4 o4;
            #pragma unroll
            for (int c = 0; c < 4; ++c) {
                float o = (y[c] - mu)*rs*((const float*)&g4)[c] + ((const float*)&b4)[c];
                if (!(o == o)) o = 12345.0f;  // NaN sentinel (never hit on a passing run)
                ((float*)&o4)[c] = o;
            }
            *(float4*)(fout + base) = o4;
        }
    }
}

extern "C" void kernel_launch(void* const* d_in, const int* in_sizes, int n_in,
                              void* d_out, int out_size, void* d_ws, size_t ws_size,
                              hipStream_t stream)
{
    const float* x   = (const float*)d_in[0];
    // d_in[1] = emb is dead: adj = sigmoid(l2norm(emb)@l2norm(emb)^T) in [0.27,1],
    // diag forced 1 -> adj==0 never true -> dense attention.
    const float* q1w = (const float*)d_in[2];
    const float* q1b = (const float*)d_in[3];
    const float* k1w = (const float*)d_in[4];
    const float* k1b = (const float*)d_in[5];
    const float* v1w = (const float*)d_in[6];
    const float* v1b = (const float*)d_in[7];
    const float* q2w = (const float*)d_in[8];
    const float* q2b = (const float*)d_in[9];
    const float* k2w = (const float*)d_in[10];
    const float* k2b = (const float*)d_in[11];
    const float* v2w = (const float*)d_in[12];
    const float* v2b = (const float*)d_in[13];
    const float* pw  = (const float*)d_in[14];
    const float* lng = (const float*)d_in[15];
    const float* lnb = (const float*)d_in[16];

    const size_t SZ = (size_t)NB*NN*DOUT;           // 1,048,576 elements
    char* wsb = (char*)d_ws;
    bf16*  qA   = (bf16*)(wsb + 0*SZ*2);            // [0,2) MB  fragment-linear
    bf16*  kA   = (bf16*)(wsb + 1*SZ*2);            // [2,4) MB
    bf16*  vT   = (bf16*)(wsb + 2*SZ*2);            // [4,6) MB
    float* proj = (float*)(wsb + 3*SZ*2);           // [6,10) MB
    bf16*  h    = (bf16*)(wsb + 3*SZ*2 + SZ*4);     // [10,12) MB

    k_gemm1<<<dim3(128, 8), 256, 0, stream>>>(x, q1w, q1b, k1w, k1b, v1w, v1b, pw,
                                              qA, kA, vT, proj);
    // MODE0: NQ=4, NW=8 -> 512 blocks, 512 threads
    k_attn_mfma<32, 0, 8, 4><<<dim3(32, 16), 512, 0, stream>>>(
        qA, kA, vT, nullptr, nullptr, nullptr, h, nullptr);
    k_gemm2<<<dim3(128, 6), 256, 0, stream>>>(h, q2w, q2b, k2w, k2b, v2w, v2b,
                                              qA, kA, vT);
    // MODE1: NQ=2, NW=8 -> 256 blocks, 512 threads
    k_attn_mfma<128, 1, 8, 2><<<dim3(64, 4), 512, 0, stream>>>(
        qA, kA, vT, proj, lng, lnb, nullptr, (float*)d_out);
}